// Round 6
// baseline (176.261 us; speedup 1.0000x reference)
//
#include <hip/hip_runtime.h>

#define LL 512
#define BB 32
#define TT 48
#define GROW 5.0f
#define ENEG 6.737946999085467e-03f   // exp(-GROW)

typedef _Float16 f16x2 __attribute__((ext_vector_type(2)));
typedef _Float16 f16x4 __attribute__((ext_vector_type(4)));
typedef float    f32x4 __attribute__((ext_vector_type(4)));

// workspace layout (bytes)
#define WS_U   0                          // [512][2 waves][64 lanes][8 dwords] = 2 MB
#define WS_V0  (512 * 2 * 64 * 32)        // [2][64][8 dwords]
#define WS_C0  (WS_V0 + 2 * 64 * 32)
#define WS_M0  (WS_C0 + 2 * 64 * 32)      // 32 floats

__device__ __forceinline__ f16x4 mk4(unsigned lo, unsigned hi) {
  unsigned long long uu = (unsigned long long)lo | ((unsigned long long)hi << 32);
  return __builtin_bit_cast(f16x4, uu);
}

// cvt_pkrtz returns __fp16 vector type; bit_cast to our f16x2
__device__ __forceinline__ f16x2 pkrtz(float a, float b) {
  return __builtin_bit_cast(f16x2, __builtin_amdgcn_cvt_pkrtz(a, b));
}

// ---------------- prep: stage u = exp(0.5E) (packed f16, per-lane layout) + init state ----------------
__global__ __launch_bounds__(128, 1)
void prep_kernel(const float* __restrict__ E, const int* __restrict__ mask,
                 const float* __restrict__ st, float* __restrict__ ws_)
{
  const int j = blockIdx.x;
  const int tid = threadIdx.x;
  const int w = tid >> 6, l = tid & 63;
  const int g = l >> 4, b = w * 16 + (l & 15);
  char* ws = (char*)ws_;
  __shared__ float Et[BB * TT];
  for (int i = tid; i < BB * TT; i += 128) Et[i] = E[(size_t)j * BB * TT + i];
  __syncthreads();

  unsigned dws[6];
  #pragma unroll
  for (int blk = 0; blk < 3; ++blk)
    #pragma unroll
    for (int h = 0; h < 2; ++h) {
      const int t0 = 16 * blk + 4 * g + 2 * h;
      f16x2 p = pkrtz(__expf(0.5f * Et[b * TT + t0]),
                      __expf(0.5f * Et[b * TT + t0 + 1]));
      dws[2 * blk + h] = __builtin_bit_cast(unsigned, p);
    }
  uint4 s0 = {dws[0], dws[1], dws[2], dws[3]};
  uint4 s1 = {dws[4], dws[5], __float_as_uint(mask[j * BB + b] ? 1.f : 0.f), 0u};
  uint4* dst = (uint4*)(ws + WS_U + (size_t)((j * 2 + w) * 64 + l) * 32);
  dst[0] = s0; dst[1] = s1;

  if (j == 0) {
    const float M0 = st[0] + Et[b * TT + 0];
    unsigned v0d[6], c0d[6];
    #pragma unroll
    for (int blk = 0; blk < 3; ++blk)
      #pragma unroll
      for (int h = 0; h < 2; ++h) {
        const int t0 = 16 * blk + 4 * g + 2 * h;
        const float a0 = st[t0] + Et[b * TT + t0] - M0;
        const float a1 = st[t0 + 1] + Et[b * TT + t0 + 1] - M0;
        v0d[2 * blk + h] = __builtin_bit_cast(unsigned, pkrtz(__expf(a0), __expf(a1)));
        const float c0 = __expf(st[t0] - M0) * __expf(0.5f * Et[b * TT + t0]);
        const float c1 = __expf(st[t0 + 1] - M0) * __expf(0.5f * Et[b * TT + t0 + 1]);
        c0d[2 * blk + h] = __builtin_bit_cast(unsigned, pkrtz(c0, c1));
      }
    uint4* dv = (uint4*)(ws + WS_V0 + (size_t)(w * 64 + l) * 32);
    uint4* dc = (uint4*)(ws + WS_C0 + (size_t)(w * 64 + l) * 32);
    dv[0] = (uint4){v0d[0], v0d[1], v0d[2], v0d[3]};
    dv[1] = (uint4){v0d[4], v0d[5], 0u, 0u};
    dc[0] = (uint4){c0d[0], c0d[1], c0d[2], c0d[3]};
    dc[1] = (uint4){c0d[4], c0d[5], 0u, 0u};
    if (l < 16) ((float*)(ws + WS_M0))[b] = M0;
  }
}

// ---------------- numerator: one block per batch, one lane per segment ----------------
__global__ __launch_bounds__(64, 1)
void numer_kernel(const float* __restrict__ E, const int* __restrict__ tags,
                  const int* __restrict__ lens, const int* __restrict__ mask,
                  const float* __restrict__ st, const float* __restrict__ et,
                  const float* __restrict__ tr, float* __restrict__ out)
{
  const int b = blockIdx.x;
  const int s = threadIdx.x;
  const int lenv = lens[s * BB + b];
  int pre = lenv;
  #pragma unroll
  for (int off = 1; off < 64; off <<= 1) {
    int y = __shfl_up(pre, off, 64);
    if (s >= off) pre += y;
  }
  int ms = 0;
  #pragma unroll
  for (int kk = 0; kk < LL / 64; ++kk) ms += mask[(s + 64 * kk) * BB + b];
  #pragma unroll
  for (int off = 32; off; off >>= 1) ms += __shfl_xor(ms, off, 64);
  const int max_idx = (ms < LL - 1) ? ms : (LL - 1);
  float term;
  if (s == 0) {
    const int tag0 = tags[b];
    int i1 = lenv - 1; if (i1 < 0) i1 = 0; if (i1 > LL - 1) i1 = LL - 1;
    const float se = 0.5f * (E[b * TT + tag0] + E[(i1 * BB + b) * TT + tag0]);
    int send = ms - 1; if (send < 0) send = 0; if (send > LL - 1) send = LL - 1;
    term = st[tag0] + se + et[tags[send * BB + b]];
  } else {
    int startp = pre - lenv;
    if (startp > max_idx) startp = max_idx;
    int endp1 = startp + lenv - 1; if (endp1 > LL - 1) endp1 = LL - 1;
    int sm1 = startp - 1; if (sm1 < 0) sm1 = 0;
    const int  stg = tags[startp * BB + b];
    const int  ptg = tags[sm1 * BB + b];
    const int  etg = tags[endp1 * BB + b];
    const float m  = (float)mask[startp * BB + b];
    const float se = 0.5f * (E[(startp * BB + b) * TT + stg] + E[(endp1 * BB + b) * TT + stg]);
    term = (se + tr[ptg * TT + etg]) * m;
  }
  #pragma unroll
  for (int off = 32; off; off >>= 1) term += __shfl_xor(term, off, 64);
  if (s == 0) atomicAdd(out, term);
}

// ---------------- scan: 1 wave per 16 batches; MFMA recurrence, all in-lane ----------------
__global__ __launch_bounds__(64, 1)
void scan_kernel(const float* __restrict__ tr, const float* __restrict__ et,
                 const float* __restrict__ ws_, float* __restrict__ out)
{
  const int w = blockIdx.x;      // 0,1 -> batches w*16 .. w*16+15
  const int l = threadIdx.x;
  const int g = l >> 4;
  const char* ws = (const char*)ws_;

  // A = W^T fragments: A[mb][kb]; lane holds A[m][k], m = 16mb+(l&15), k = 16kb+4g+i
  f16x4 A[3][3];
  #pragma unroll
  for (int mb = 0; mb < 3; ++mb)
    #pragma unroll
    for (int kb = 0; kb < 3; ++kb) {
      f16x4 a;
      #pragma unroll
      for (int i = 0; i < 4; ++i)
        a[i] = (_Float16)__expf(tr[(16 * kb + 4 * g + i) * TT + 16 * mb + (l & 15)]);
      // pin in VGPRs (r2 lesson: allocator sinks loop-invariant loads otherwise)
      unsigned long long aa = __builtin_bit_cast(unsigned long long, a);
      asm volatile("" : "+v"(aa));
      A[mb][kb] = __builtin_bit_cast(f16x4, aa);
    }

  // init state
  const uint4* iv = (const uint4*)(ws + WS_V0 + (size_t)(w * 64 + l) * 32);
  const uint4* ic = (const uint4*)(ws + WS_C0 + (size_t)(w * 64 + l) * 32);
  const uint4 v01 = iv[0], v2_ = iv[1];
  const uint4 c01 = ic[0], c2_ = ic[1];
  unsigned vd[6] = {v01.x, v01.y, v01.z, v01.w, v2_.x, v2_.y};
  f16x2 C[6];
  C[0] = __builtin_bit_cast(f16x2, c01.x); C[1] = __builtin_bit_cast(f16x2, c01.y);
  C[2] = __builtin_bit_cast(f16x2, c01.z); C[3] = __builtin_bit_cast(f16x2, c01.w);
  C[4] = __builtin_bit_cast(f16x2, c2_.x); C[5] = __builtin_bit_cast(f16x2, c2_.y);
  float Mcur = ((const float*)(ws + WS_M0))[w * 16 + (l & 15)];
  float v0next = 1.0f;                     // P_0[0] = 1 by construction

  // u prefetch ring (4 steps deep; stride per j = 2*64*32 = 4096 B)
  const char* Ub = ws + WS_U + (size_t)(w * 64 + l) * 32;
  uint4 ua[4], ub[4];
  #pragma unroll
  for (int q = 0; q < 4; ++q) {
    ua[(q + 1) & 3] = *(const uint4*)(Ub + (size_t)(q + 1) * 4096);
    ub[(q + 1) & 3] = *(const uint4*)(Ub + (size_t)(q + 1) * 4096 + 16);
  }

  const f32x4 zero4 = {0.f, 0.f, 0.f, 0.f};

  auto step = [&](int j, int p) {
    // matvec PA = W^T . v  (D-layout == next B-layout: stays in-lane)
    const f16x4 B0 = mk4(vd[0], vd[1]);
    const f16x4 B1 = mk4(vd[2], vd[3]);
    const f16x4 B2 = mk4(vd[4], vd[5]);
    f32x4 D0 = __builtin_amdgcn_mfma_f32_16x16x16f16(A[0][0], B0, zero4, 0, 0, 0);
    f32x4 D1 = __builtin_amdgcn_mfma_f32_16x16x16f16(A[1][0], B0, zero4, 0, 0, 0);
    f32x4 D2 = __builtin_amdgcn_mfma_f32_16x16x16f16(A[2][0], B0, zero4, 0, 0, 0);
    D0 = __builtin_amdgcn_mfma_f32_16x16x16f16(A[0][1], B1, D0, 0, 0, 0);
    D1 = __builtin_amdgcn_mfma_f32_16x16x16f16(A[1][1], B1, D1, 0, 0, 0);
    D2 = __builtin_amdgcn_mfma_f32_16x16x16f16(A[2][1], B1, D2, 0, 0, 0);
    D0 = __builtin_amdgcn_mfma_f32_16x16x16f16(A[0][2], B2, D0, 0, 0, 0);
    D1 = __builtin_amdgcn_mfma_f32_16x16x16f16(A[1][2], B2, D1, 0, 0, 0);
    D2 = __builtin_amdgcn_mfma_f32_16x16x16f16(A[2][2], B2, D2, 0, 0, 0);

    // normalizer (delay-1 feedback; M increment matches applied eg up to ulps)
    const float eg = __builtin_amdgcn_rcpf(v0next) * ENEG;
    Mcur += GROW + __logf(v0next);
    const f16x2 egpk = pkrtz(eg, eg);

    // consume u slot, then refill for j+4
    const uint4 uA = ua[p], uB = ub[p];
    int jn = j + 4; if (jn > LL - 1) jn = LL - 1;
    ua[p] = *(const uint4*)(Ub + (size_t)jn * 4096);
    ub[p] = *(const uint4*)(Ub + (size_t)jn * 4096 + 16);
    const float mf = __uint_as_float(uB.z);
    const unsigned udw[6] = {uA.x, uA.y, uA.z, uA.w, uB.x, uB.y};
    const float Dv[12] = {D0[0], D0[1], D0[2], D0[3],
                          D1[0], D1[1], D1[2], D1[3],
                          D2[0], D2[1], D2[2], D2[3]};

    #pragma unroll
    for (int d6 = 0; d6 < 6; ++d6) {
      const f16x2 pa = pkrtz(Dv[2 * d6], Dv[2 * d6 + 1]);
      const f16x2 ud = __builtin_bit_cast(f16x2, udw[d6]);
      const f16x2 z  = pa * ud;                 // z_j = u ∘ PA
      const f16x2 Cn = (C[d6] + z) * egpk;      // leaky integrator (K->inf, err < e^-16 rel)
      C[d6] = Cn;
      const f16x2 vn = ud * Cn;                 // v_j = u ∘ C
      const f16x2 va = __builtin_bit_cast(f16x2, vd[d6]) * egpk;  // masked: hold alpha
      vd[d6] = (mf > 0.f) ? __builtin_bit_cast(unsigned, vn)
                          : __builtin_bit_cast(unsigned, va);
    }
    // broadcast P_j[0] per batch column: FULL-WAVE bpermute (ds_swizzle is
    // 32-lane-scoped -> upper half read tag-8 row, diverging scales -> NaN; r5 bug)
    const float v0f = (float)__builtin_bit_cast(f16x2, vd[0]).x;
    v0next = __shfl(v0f, l & 15, 64);
  };

  for (int c = 0; c < 127; ++c) {
    const int j = 4 * c + 1;
    step(j + 0, 1); step(j + 1, 2); step(j + 2, 3); step(j + 3, 0);
  }
  step(509, 1); step(510, 2); step(511, 3);

  // epilogue: denom_b = M_511 + log(sum_t v[t,b] * exp(et[t]))
  float s = 0.f;
  #pragma unroll
  for (int blk = 0; blk < 3; ++blk)
    #pragma unroll
    for (int h = 0; h < 2; ++h) {
      const int t0 = 16 * blk + 4 * g + 2 * h;
      const f16x2 vp = __builtin_bit_cast(f16x2, vd[2 * blk + h]);
      s += (float)vp.x * __expf(et[t0]) + (float)vp.y * __expf(et[t0 + 1]);
    }
  s += __shfl_xor(s, 16, 64);
  s += __shfl_xor(s, 32, 64);
  float den = Mcur + __logf(s);            // duplicated x4 per batch column
  #pragma unroll
  for (int off = 1; off < 16; off <<= 1) den += __shfl_xor(den, off, 64);
  if (l == 0) atomicAdd(out, -den);        // lane0 group-sum = 16 batches' denoms
}

extern "C" void kernel_launch(void* const* d_in, const int* in_sizes, int n_in,
                              void* d_out, int out_size, void* d_ws, size_t ws_size,
                              hipStream_t stream) {
  (void)in_sizes; (void)n_in; (void)ws_size;
  const float* E    = (const float*)d_in[0];
  const int*   tags = (const int*)d_in[1];
  const int*   lens = (const int*)d_in[2];
  const int*   mask = (const int*)d_in[3];
  const float* st   = (const float*)d_in[4];
  const float* et   = (const float*)d_in[5];
  const float* tr   = (const float*)d_in[6];
  float* out = (float*)d_out;
  (void)hipMemsetAsync(out, 0, out_size * sizeof(float), stream);
  prep_kernel<<<dim3(LL), dim3(128), 0, stream>>>(E, mask, st, (float*)d_ws);
  numer_kernel<<<dim3(BB), dim3(64), 0, stream>>>(E, tags, lens, mask, st, et, tr, out);
  scan_kernel<<<dim3(2), dim3(64), 0, stream>>>(tr, et, (const float*)d_ws, out);
}